// Round 13
// baseline (498.314 us; speedup 1.0000x reference)
//
#include <hip/hip_runtime.h>
#include <math.h>

typedef __bf16 bf16_t;
typedef __attribute__((ext_vector_type(8))) __bf16 bf16x8;
typedef __attribute__((ext_vector_type(4))) __bf16 bf16x4;
typedef __attribute__((ext_vector_type(4))) float f32x4;

#define DMODEL 1024
#define NROWS  16384   // B*T
#define SEQLEN 4096

static __device__ __forceinline__ float sigmoidf_(float v) { return 1.f / (1.f + __expf(-v)); }
static __device__ __forceinline__ float tanhf_(float v) {
  v = fminf(fmaxf(v, -15.f), 15.f);
  float e = __expf(-2.f * v);
  return (1.f - e) / (1.f + e);
}

#define GLOAD16(gsrc, ldst) __builtin_amdgcn_global_load_lds(                     \
    (const __attribute__((address_space(1))) void*)(gsrc),                        \
    (__attribute__((address_space(3))) void*)(ldst), 16, 0, 0)

// ---------------- fused LayerNorm (f32 in): stats + apply + f32->bf16 ----------------
__global__ __launch_bounds__(256) void ln_fused_kernel(const float* __restrict__ x,
                                                       const float* __restrict__ g,
                                                       const float* __restrict__ b,
                                                       bf16_t* __restrict__ out) {
  int row = blockIdx.x;
  int tid = threadIdx.x;
  const float4* xr = (const float4*)(x + (size_t)row * DMODEL);
  float4 v = xr[tid];
  float s  = v.x + v.y + v.z + v.w;
  float s2 = v.x*v.x + v.y*v.y + v.z*v.z + v.w*v.w;
  #pragma unroll
  for (int off = 32; off > 0; off >>= 1) {
    s  += __shfl_down(s, off);
    s2 += __shfl_down(s2, off);
  }
  __shared__ float sh[4], sh2[4];
  int lane = tid & 63, wid = tid >> 6;
  if (lane == 0) { sh[wid] = s; sh2[wid] = s2; }
  __syncthreads();
  s  = sh[0] + sh[1] + sh[2] + sh[3];
  s2 = sh2[0] + sh2[1] + sh2[2] + sh2[3];
  float m = s * (1.f / DMODEL);
  float var = fmaxf(s2 * (1.f / DMODEL) - m * m, 0.f);
  float rs = rsqrtf(var + 1e-5f);
  float4 gv = *(const float4*)&g[tid * 4];
  float4 bv = *(const float4*)&b[tid * 4];
  union { bf16_t h[4]; float2 f2; } u;
  u.h[0] = (bf16_t)((v.x - m) * rs * gv.x + bv.x);
  u.h[1] = (bf16_t)((v.y - m) * rs * gv.y + bv.y);
  u.h[2] = (bf16_t)((v.z - m) * rs * gv.z + bv.z);
  u.h[3] = (bf16_t)((v.w - m) * rs * gv.w + bv.w);
  *(float2*)&out[(size_t)row * DMODEL + tid * 4] = u.f2;
}

// ---------------- fused LayerNorm (bf16 in) ----------------
__global__ __launch_bounds__(256) void ln_fused_bf16_kernel(const bf16_t* __restrict__ x,
                                                            const float* __restrict__ g,
                                                            const float* __restrict__ b,
                                                            bf16_t* __restrict__ out) {
  int row = blockIdx.x;
  int tid = threadIdx.x;
  bf16x4 hv = *(const bf16x4*)(x + (size_t)row * DMODEL + tid * 4);
  float v0 = (float)hv[0], v1 = (float)hv[1], v2 = (float)hv[2], v3 = (float)hv[3];
  float s  = v0 + v1 + v2 + v3;
  float s2 = v0*v0 + v1*v1 + v2*v2 + v3*v3;
  #pragma unroll
  for (int off = 32; off > 0; off >>= 1) {
    s  += __shfl_down(s, off);
    s2 += __shfl_down(s2, off);
  }
  __shared__ float sh[4], sh2[4];
  int lane = tid & 63, wid = tid >> 6;
  if (lane == 0) { sh[wid] = s; sh2[wid] = s2; }
  __syncthreads();
  s  = sh[0] + sh[1] + sh[2] + sh[3];
  s2 = sh2[0] + sh2[1] + sh2[2] + sh2[3];
  float m = s * (1.f / DMODEL);
  float var = fmaxf(s2 * (1.f / DMODEL) - m * m, 0.f);
  float rs = rsqrtf(var + 1e-5f);
  float4 gv = *(const float4*)&g[tid * 4];
  float4 bv = *(const float4*)&b[tid * 4];
  union { bf16_t h[4]; float2 f2; } u;
  u.h[0] = (bf16_t)((v0 - m) * rs * gv.x + bv.x);
  u.h[1] = (bf16_t)((v1 - m) * rs * gv.y + bv.y);
  u.h[2] = (bf16_t)((v2 - m) * rs * gv.z + bv.z);
  u.h[3] = (bf16_t)((v3 - m) * rs * gv.w + bv.w);
  *(float2*)&out[(size_t)row * DMODEL + tid * 4] = u.f2;
}

// ---------------- batched f32 -> bf16 weight conversion (one kernel, 5 segments) ----------------
// dst regions are contiguous bf16 starting at dstb: W_in(128K f32) | W_sel(128K) | W_g(1M) | W1(4M) | W2(4M)
__global__ __launch_bounds__(256) void conv_all_kernel(
    const float* __restrict__ W_in, const float* __restrict__ W_sel,
    const float* __restrict__ W_g, const float* __restrict__ W1,
    const float* __restrict__ W2, bf16_t* __restrict__ dstb) {
  int q = blockIdx.x * 256 + threadIdx.x;   // quad index, < 2424832
  size_t e = (size_t)q * 4;                 // f32 element offset in flat dst space
  const float* src;
  size_t off;
  if (e < 131072)        { src = W_in;  off = e; }
  else if (e < 262144)   { src = W_sel; off = e - 131072; }
  else if (e < 1310720)  { src = W_g;   off = e - 262144; }
  else if (e < 5505024)  { src = W1;    off = e - 1310720; }
  else                   { src = W2;    off = e - 5505024; }
  float4 v = *(const float4*)&src[off];
  union { bf16_t h[4]; float2 f2; } u;
  u.h[0] = (bf16_t)v.x; u.h[1] = (bf16_t)v.y; u.h[2] = (bf16_t)v.z; u.h[3] = (bf16_t)v.w;
  *(float2*)&dstb[e] = u.f2;
}

// ================= Engine B (r7-proven): 128x256 / BK=64 / single-buffer 48KB / 8 waves =======
// C[M,N] = A[M,K]*B[N,K]^T. 512 thr, waves 2(M)x4(N), wave tile 64x64 -> acc 64 f32.
// 2 barriers/K-tile; 2 blocks/CU co-resident hide the stage drain (m114). Swizzle: conflicts=0 (r7 PMC).
// EPI: 0 outf=acc; 1 outb=bf16(silu(acc+bias)); 2 outf=(float)resb+bias+acc; 3 outf+=acc; 5 outb=bf16(acc)
template<int EPI>
__global__ __launch_bounds__(512, 4) void gemmB_kernel(
    const bf16_t* __restrict__ A, int lda,
    const bf16_t* __restrict__ B, int ldb, int K, int nx,
    const float* __restrict__ bias,
    const bf16_t* __restrict__ resb,
    float* __restrict__ outf, bf16_t* __restrict__ outb, int ldout) {
  __shared__ __align__(128) bf16_t Asm[128 * 64];   // 16 KB
  __shared__ __align__(128) bf16_t Bsm[256 * 64];   // 32 KB
  const int nwg = gridDim.x;
  const int bid = blockIdx.x;
  const int lid = (bid & 7) * (nwg >> 3) + (bid >> 3);   // bijective XCD swizzle (nwg%8==0)
  const int n0 = (lid % nx) * 256;
  const int r0 = (lid / nx) * 128;

  const int tid = threadIdx.x;
  const int lane = tid & 63;
  const int w = tid >> 6;
  const int wr = w >> 2, wc = w & 3;        // 2 x 4 wave grid
  const int fr = lane & 15;
  const int q16 = (lane >> 4) * 16;         // k-byte base within 64-bf16 row half
  const int swz = (fr & 7) << 4;
  const int trow = tid >> 3;                // staging row 0..63
  const int scolb = ((tid & 7) ^ (trow & 7)) << 4;

  const size_t lda_b = (size_t)lda * 2;
  const size_t ldb_b = (size_t)ldb * 2;
  const char* Ab = (const char*)A;
  const char* Bb = (const char*)B;
  char* lA = (char*)Asm;
  char* lB = (char*)Bsm;

  f32x4 acc[4][4];
  #pragma unroll
  for (int m = 0; m < 4; ++m)
    #pragma unroll
    for (int n = 0; n < 4; ++n) acc[m][n] = (f32x4){0.f, 0.f, 0.f, 0.f};

  for (int kt = 0; kt < K; kt += 64) {
    const char* sa = Ab + (size_t)(r0 + trow) * lda_b + kt * 2 + scolb;
    GLOAD16(sa, lA + tid * 16);
    GLOAD16(sa + 64 * lda_b, lA + 8192 + tid * 16);
    const char* sb = Bb + (size_t)(n0 + trow) * ldb_b + kt * 2 + scolb;
    GLOAD16(sb, lB + tid * 16);
    GLOAD16(sb + 64 * ldb_b,  lB + 8192  + tid * 16);
    GLOAD16(sb + 128 * ldb_b, lB + 16384 + tid * 16);
    GLOAD16(sb + 192 * ldb_b, lB + 24576 + tid * 16);
    __syncthreads();
    #pragma unroll
    for (int kh = 0; kh < 2; ++kh) {
      bf16x8 af[4], bv[4];
      #pragma unroll
      for (int m = 0; m < 4; ++m)
        af[m] = *(const bf16x8*)(lA + (wr * 64 + m * 16 + fr) * 128 + ((kh * 64 + q16) ^ swz));
      #pragma unroll
      for (int n = 0; n < 4; ++n)
        bv[n] = *(const bf16x8*)(lB + (wc * 64 + n * 16 + fr) * 128 + ((kh * 64 + q16) ^ swz));
      #pragma unroll
      for (int m = 0; m < 4; ++m)
        #pragma unroll
        for (int n = 0; n < 4; ++n)
          acc[m][n] = __builtin_amdgcn_mfma_f32_16x16x32_bf16(af[m], bv[n], acc[m][n], 0, 0, 0);
    }
    __syncthreads();
  }

  const int rbase = (lane >> 4) * 4;
  #pragma unroll
  for (int mf = 0; mf < 4; ++mf) {
    #pragma unroll
    for (int n = 0; n < 4; ++n) {
      int row = r0 + wr * 64 + mf * 16 + rbase;
      int col = n0 + wc * 64 + n * 16 + fr;
      f32x4 v = acc[mf][n];
      #pragma unroll
      for (int j = 0; j < 4; ++j) {
        int r = row + j;
        float val = v[j];
        if (EPI == 0) {
          outf[(size_t)r * ldout + col] = val;
        } else if (EPI == 1) {
          float t2 = val + bias[col];
          t2 = t2 * sigmoidf_(t2);
          outb[(size_t)r * ldout + col] = (bf16_t)t2;
        } else if (EPI == 2) {
          outf[(size_t)r * ldout + col] =
              (float)resb[(size_t)r * 1024 + col] + bias[col] + val;
        } else if (EPI == 3) {
          outf[(size_t)r * ldout + col] += val;
        } else {
          outb[(size_t)r * ldout + col] = (bf16_t)val;
        }
      }
    }
  }
}

// ======= fused gate + h-projection (engine-B geometry): two K-loops, one epilogue =======
// accg = xn[128rows] @ Wg[256cols]^T (K=1024); acch = cc @ Weff^T (K=128);
// xmid = bf16( x + sigmoid(accg + b_g) * acch ).  Grid 512 (nx=4).
__global__ __launch_bounds__(512, 4) void gateh_kernel(
    const bf16_t* __restrict__ xn, const bf16_t* __restrict__ Wg,
    const bf16_t* __restrict__ cc, const bf16_t* __restrict__ Wef,
    const float* __restrict__ x, const float* __restrict__ b_g,
    bf16_t* __restrict__ xmid) {
  __shared__ __align__(128) bf16_t Asm[128 * 64];
  __shared__ __align__(128) bf16_t Bsm[256 * 64];
  const int nwg = gridDim.x;
  const int bid = blockIdx.x;
  const int lid = (bid & 7) * (nwg >> 3) + (bid >> 3);
  const int n0 = (lid & 3) * 256;        // nx = 4
  const int r0 = (lid >> 2) * 128;

  const int tid = threadIdx.x;
  const int lane = tid & 63;
  const int w = tid >> 6;
  const int wr = w >> 2, wc = w & 3;
  const int fr = lane & 15;
  const int q16 = (lane >> 4) * 16;
  const int swz = (fr & 7) << 4;
  const int trow = tid >> 3;
  const int scolb = ((tid & 7) ^ (trow & 7)) << 4;
  char* lA = (char*)Asm;
  char* lB = (char*)Bsm;

  f32x4 accg[4][4], acch[4][4];
  #pragma unroll
  for (int m = 0; m < 4; ++m)
    #pragma unroll
    for (int n = 0; n < 4; ++n) {
      accg[m][n] = (f32x4){0.f, 0.f, 0.f, 0.f};
      acch[m][n] = (f32x4){0.f, 0.f, 0.f, 0.f};
    }

  // ---- loop 1: gate, K=1024, lda=ldb=1024 ----
  for (int kt = 0; kt < 1024; kt += 64) {
    const char* sa = (const char*)xn + (size_t)(r0 + trow) * 2048 + kt * 2 + scolb;
    GLOAD16(sa, lA + tid * 16);
    GLOAD16(sa + 64 * 2048, lA + 8192 + tid * 16);
    const char* sb = (const char*)Wg + (size_t)(n0 + trow) * 2048 + kt * 2 + scolb;
    GLOAD16(sb, lB + tid * 16);
    GLOAD16(sb + 64 * 2048,  lB + 8192  + tid * 16);
    GLOAD16(sb + 128 * 2048, lB + 16384 + tid * 16);
    GLOAD16(sb + 192 * 2048, lB + 24576 + tid * 16);
    __syncthreads();
    #pragma unroll
    for (int kh = 0; kh < 2; ++kh) {
      bf16x8 af[4], bv[4];
      #pragma unroll
      for (int m = 0; m < 4; ++m)
        af[m] = *(const bf16x8*)(lA + (wr * 64 + m * 16 + fr) * 128 + ((kh * 64 + q16) ^ swz));
      #pragma unroll
      for (int n = 0; n < 4; ++n)
        bv[n] = *(const bf16x8*)(lB + (wc * 64 + n * 16 + fr) * 128 + ((kh * 64 + q16) ^ swz));
      #pragma unroll
      for (int m = 0; m < 4; ++m)
        #pragma unroll
        for (int n = 0; n < 4; ++n)
          accg[m][n] = __builtin_amdgcn_mfma_f32_16x16x32_bf16(af[m], bv[n], accg[m][n], 0, 0, 0);
    }
    __syncthreads();
  }

  // ---- loop 2: h-projection, K=128, lda=ldb=128 ----
  for (int kt = 0; kt < 128; kt += 64) {
    const char* sa = (const char*)cc + (size_t)(r0 + trow) * 256 + kt * 2 + scolb;
    GLOAD16(sa, lA + tid * 16);
    GLOAD16(sa + 64 * 256, lA + 8192 + tid * 16);
    const char* sb = (const char*)Wef + (size_t)(n0 + trow) * 256 + kt * 2 + scolb;
    GLOAD16(sb, lB + tid * 16);
    GLOAD16(sb + 64 * 256,  lB + 8192  + tid * 16);
    GLOAD16(sb + 128 * 256, lB + 16384 + tid * 16);
    GLOAD16(sb + 192 * 256, lB + 24576 + tid * 16);
    __syncthreads();
    #pragma unroll
    for (int kh = 0; kh < 2; ++kh) {
      bf16x8 af[4], bv[4];
      #pragma unroll
      for (int m = 0; m < 4; ++m)
        af[m] = *(const bf16x8*)(lA + (wr * 64 + m * 16 + fr) * 128 + ((kh * 64 + q16) ^ swz));
      #pragma unroll
      for (int n = 0; n < 4; ++n)
        bv[n] = *(const bf16x8*)(lB + (wc * 64 + n * 16 + fr) * 128 + ((kh * 64 + q16) ^ swz));
      #pragma unroll
      for (int m = 0; m < 4; ++m)
        #pragma unroll
        for (int n = 0; n < 4; ++n)
          acch[m][n] = __builtin_amdgcn_mfma_f32_16x16x32_bf16(af[m], bv[n], acch[m][n], 0, 0, 0);
    }
    __syncthreads();
  }

  const int rbase = (lane >> 4) * 4;
  #pragma unroll
  for (int mf = 0; mf < 4; ++mf) {
    #pragma unroll
    for (int n = 0; n < 4; ++n) {
      int row = r0 + wr * 64 + mf * 16 + rbase;
      int col = n0 + wc * 64 + n * 16 + fr;
      #pragma unroll
      for (int j = 0; j < 4; ++j) {
        size_t idx = (size_t)(row + j) * 1024 + col;
        xmid[idx] = (bf16_t)(x[idx] + sigmoidf_(accg[mf][n][j] + b_g[col]) * acch[mf][n][j]);
      }
    }
  }
}

// ---------------- legacy 128x128 engine (beta/delta swapped GEMM only) ----------------
template<int EPI>
__global__ __launch_bounds__(256) void gemm_bf16_kernel(
    const bf16_t* __restrict__ A, int lda,
    const bf16_t* __restrict__ B, int ldb, int K, int nx,
    float* __restrict__ outf, int ldout) {
  __shared__ __align__(16) bf16_t As[128 * 32];
  __shared__ __align__(16) bf16_t Bs[128 * 32];
  const int nwg = gridDim.x;
  const int bid = blockIdx.x;
  const int lid = (bid & 7) * (nwg >> 3) + (bid >> 3);
  const int n0 = (lid % nx) * 128;
  const int r0 = (lid / nx) * 128;

  const int tid = threadIdx.x;
  const int lane = tid & 63;
  const int w = tid >> 6;
  const int wr = w >> 1, wc = w & 1;
  const int srow0 = tid >> 2;
  const int srow1 = 64 + (tid >> 2);
  const int skk = (tid & 3) * 8;
  const int fr = lane & 15;
  const int ko = (lane >> 4) * 8;

  f32x4 acc[4][4];
  #pragma unroll
  for (int m = 0; m < 4; ++m)
    #pragma unroll
    for (int n = 0; n < 4; ++n) acc[m][n] = (f32x4){0.f, 0.f, 0.f, 0.f};

  for (int k0 = 0; k0 < K; k0 += 32) {
    GLOAD16(A + (size_t)(r0 + srow0) * lda + k0 + skk, (char*)As + w * 1024);
    GLOAD16(A + (size_t)(r0 + srow1) * lda + k0 + skk, (char*)As + 4096 + w * 1024);
    GLOAD16(B + (size_t)(n0 + srow0) * ldb + k0 + skk, (char*)Bs + w * 1024);
    GLOAD16(B + (size_t)(n0 + srow1) * ldb + k0 + skk, (char*)Bs + 4096 + w * 1024);
    __syncthreads();
    bf16x8 af[4], bfr[4];
    #pragma unroll
    for (int m = 0; m < 4; ++m)
      af[m] = *(const bf16x8*)&As[(wr * 64 + m * 16 + fr) * 32 + ko];
    #pragma unroll
    for (int n = 0; n < 4; ++n)
      bfr[n] = *(const bf16x8*)&Bs[(wc * 64 + n * 16 + fr) * 32 + ko];
    #pragma unroll
    for (int m = 0; m < 4; ++m)
      #pragma unroll
      for (int n = 0; n < 4; ++n)
        acc[m][n] = __builtin_amdgcn_mfma_f32_16x16x32_bf16(af[m], bfr[n], acc[m][n], 0, 0, 0);
    __syncthreads();
  }

  const int rbase = (lane >> 4) * 4;
  #pragma unroll
  for (int m = 0; m < 4; ++m) {
    #pragma unroll
    for (int n = 0; n < 4; ++n) {
      int row = r0 + wr * 64 + m * 16 + rbase;
      int col = n0 + wc * 64 + n * 16 + fr;
      f32x4 v = acc[m][n];
      #pragma unroll
      for (int j = 0; j < 4; ++j)
        outf[(size_t)(row + j) * ldout + col] = v[j];
    }
  }
}

// ---------------- fused ew + scan: bd_t[256][16384] -> c_r,c_i in [B,K,T] ----------------
__global__ __launch_bounds__(256) void scan_fused_kernel(
    const float* __restrict__ bdt,
    const float* __restrict__ log_decay, const float* __restrict__ frequency,
    const float* __restrict__ b_sel,
    float* __restrict__ c_r, float* __restrict__ c_i) {
  int seq = blockIdx.x;
  int bb = seq >> 6, k = seq & 63;
  int tid = threadIdx.x;
  size_t col = (size_t)bb * 4096 + tid * 16;
  const f32x4* pbr = (const f32x4*)(bdt + (size_t)k * 16384 + col);
  const f32x4* pbi = (const f32x4*)(bdt + (size_t)(64 + k) * 16384 + col);
  const f32x4* pdd = (const f32x4*)(bdt + (size_t)(128 + k) * 16384 + col);
  const f32x4* pdf = (const f32x4*)(bdt + (size_t)(192 + k) * 16384 + col);
  const float ld = log_decay[k], fq = frequency[k];
  const float bsd = b_sel[k], bsf = b_sel[64 + k];

  float arv[16], aiv[16], brv[16], biv[16];
  float Ar = 1.f, Ai = 0.f, Br = 0.f, Bi = 0.f;
  #pragma unroll
  for (int g = 0; g < 4; ++g) {
    f32x4 vbr = pbr[g], vbi = pbi[g], vdd = pdd[g], vdf = pdf[g];
    #pragma unroll
    for (int j = 0; j < 4; ++j) {
      int s = g * 4 + j;
      float mag = sigmoidf_(ld + 0.1f * tanhf_(vdd[j] + bsd));
      float f = fq + 0.05f * tanhf_(vdf[j] + bsf);
      float sn, cs;
      __sincosf(f, &sn, &cs);
      float ar = mag * cs, ai = mag * sn;
      float br = vbr[j], bi = vbi[j];
      arv[s] = ar; aiv[s] = ai; brv[s] = br; biv[s] = bi;
      float nBr = ar * Br - ai * Bi + br;
      float nBi = ar * Bi + ai * Br + bi;
      Br = nBr; Bi = nBi;
      float nAr = ar * Ar - ai * Ai;
      float nAi = ar * Ai + ai * Ar;
      Ar = nAr; Ai = nAi;
    }
  }

  __shared__ float sAr[256], sAi[256], sBr[256], sBi[256];
  sAr[tid] = Ar; sAi[tid] = Ai; sBr[tid] = Br; sBi[tid] = Bi;
  for (int off = 1; off < 256; off <<= 1) {
    __syncthreads();
    float pAr = 0.f, pAi = 0.f, pBr = 0.f, pBi = 0.f;
    if (tid >= off) { pAr = sAr[tid - off]; pAi = sAi[tid - off]; pBr = sBr[tid - off]; pBi = sBi[tid - off]; }
    __syncthreads();
    if (tid >= off) {
      float cAr = sAr[tid], cAi = sAi[tid], cBr = sBr[tid], cBi = sBi[tid];
      float nBr = cAr * pBr - cAi * pBi + cBr;
      float nBi = cAr * pBi + cAi * pBr + cBi;
      float nAr = cAr * pAr - cAi * pAi;
      float nAi = cAr * pAi + cAi * pAr;
      sAr[tid] = nAr; sAi[tid] = nAi; sBr[tid] = nBr; sBi[tid] = nBi;
    }
  }
  __syncthreads();
  float cr = (tid > 0) ? sBr[tid - 1] : 0.f;
  float ci = (tid > 0) ? sBi[tid - 1] : 0.f;

  float* outr = c_r + (size_t)seq * 4096 + tid * 16;
  float* outi = c_i + (size_t)seq * 4096 + tid * 16;
  #pragma unroll
  for (int g = 0; g < 4; ++g) {
    f32x4 vr, vi;
    #pragma unroll
    for (int j = 0; j < 4; ++j) {
      int s = g * 4 + j;
      float nr = arv[s] * cr - aiv[s] * ci + brv[s];
      float ni = arv[s] * ci + aiv[s] * cr + biv[s];
      cr = nr; ci = ni;
      vr[j] = cr; vi[j] = ci;
    }
    *(f32x4*)(outr + g * 4) = vr;
    *(f32x4*)(outi + g * 4) = vi;
  }
}

// ---------------- transpose c[B,K,T] -> cc[B*T, 128] bf16 ----------------
__global__ __launch_bounds__(256) void transpose_cc_kernel(
    const float* __restrict__ c_r, const float* __restrict__ c_i,
    bf16_t* __restrict__ cc) {
  __shared__ float Tr[64][65];
  __shared__ float Ti[64][65];
  int t0 = blockIdx.x * 64;
  int bb = blockIdx.y;
  int tid = threadIdx.x;
  int tt = tid & 63;
  int q = tid >> 6;
  #pragma unroll
  for (int p = 0; p < 16; ++p) {
    int k = p * 4 + q;
    size_t src = ((size_t)bb * 64 + k) * 4096 + t0 + tt;
    Tr[tt][k] = c_r[src];
    Ti[tt][k] = c_i[src];
  }
  __syncthreads();
  #pragma unroll
  for (int p = 0; p < 16; ++p) {
    int tt2 = p * 4 + q;
    int k = tid & 63;
    size_t row = (size_t)bb * 4096 + t0 + tt2;
    cc[row * 128 + k] = (bf16_t)Tr[tt2][k];
    cc[row * 128 + 64 + k] = (bf16_t)Ti[tt2][k];
  }
}

// ---------------- fold R into W_out: Weff[d][col] (bf16 out) ----------------
__global__ __launch_bounds__(256) void weff_kernel(const float* __restrict__ W_out,
                                                   const float* __restrict__ R,
                                                   bf16_t* __restrict__ Weff) {
  int idx = blockIdx.x * 256 + threadIdx.x;   // < 1024*128
  int d = idx >> 7, col = idx & 127;
  int k = col & 63, h = k >> 4, kk = k & 15;
  int off = (col < 64) ? 0 : 64;
  float s = 0.f;
  #pragma unroll
  for (int j = 0; j < 16; ++j)
    s += W_out[d * 128 + off + h * 16 + j] * R[h * 256 + j * 16 + kk];
  Weff[idx] = (bf16_t)s;
}

extern "C" void kernel_launch(void* const* d_in, const int* in_sizes, int n_in,
                              void* d_out, int out_size, void* d_ws, size_t ws_size,
                              hipStream_t stream) {
  (void)in_sizes; (void)n_in; (void)out_size;
  const float* x         = (const float*)d_in[0];
  const float* W_in      = (const float*)d_in[1];
  const float* log_decay = (const float*)d_in[2];
  const float* frequency = (const float*)d_in[3];
  const float* W_sel     = (const float*)d_in[4];
  const float* b_sel     = (const float*)d_in[5];
  const float* R         = (const float*)d_in[6];
  const float* W_out     = (const float*)d_in[7];
  const float* W_g       = (const float*)d_in[8];
  const float* b_g       = (const float*)d_in[9];
  const float* g1        = (const float*)d_in[10];
  const float* be1       = (const float*)d_in[11];
  const float* g2        = (const float*)d_in[12];
  const float* be2       = (const float*)d_in[13];
  const float* W1        = (const float*)d_in[14];
  const float* b1        = (const float*)d_in[15];
  const float* W2        = (const float*)d_in[16];
  const float* b2        = (const float*)d_in[17];
  float* out = (float*)d_out;
  float* ws  = (float*)d_ws;

  const size_t M1 = (size_t)1 << 20;
  const bool full = ws_size >= (size_t)61 * M1 * sizeof(float);   // 244 MB

  // R1 (dead before W1; overlapped by mid):
  float* bd_t = ws;                        // [0,4M)   256 x 16384 f32
  float* c_r  = ws + 4 * M1;               // [4,8M)
  float* c_i  = ws + 8 * M1;               // [8,12M)
  bf16_t* cc  = (bf16_t*)(ws + 12 * M1);   // [12,13M) 16384 x 128 bf16
  bf16_t* mid = (bf16_t*)ws;               // full: 16384x4096 bf16 [0,32M); chunked: [0,16M)
  size_t o = full ? 32 * M1 : 16 * M1;
  bf16_t* xmid  = (bf16_t*)(ws + o);            // 16384x1024 bf16 (residual stream)
  bf16_t* xn    = (bf16_t*)(ws + o + 8 * M1);   // 16384x1024 bf16
  size_t wb = o + 16 * M1;
  // contiguous bf16 weight block @ wb: Wbd(262144) | Wgb(1048576) | W1b(4194304) | W2b(4194304) | Wef
  bf16_t* Wbd = (bf16_t*)(ws + wb);
  bf16_t* Wgb = Wbd + 262144;
  bf16_t* W1b = Wgb + 1048576;
  bf16_t* W2b = W1b + 4194304;
  bf16_t* Wef = W2b + 4194304;             // 1024 x 128

  dim3 blk(256);
  dim3 blk512(512);

  // LN1 fused -> xn bf16
  ln_fused_kernel<<<NROWS, blk, 0, stream>>>(x, g1, be1, xn);

  // all weight conversions in one kernel (9699328 f32 = 2424832 quads)
  conv_all_kernel<<<9472, blk, 0, stream>>>(W_in, W_sel, W_g, W1, W2, Wbd);
  weff_kernel<<<512, blk, 0, stream>>>(W_out, R, Wef);

  // beta/delta GEMM SWAPPED: bd_t[j][t] = Wbd[j]·xn[t]  (M=256,N=16384,K=1024; grid 256, nx=128)
  gemm_bf16_kernel<0><<<256, blk, 0, stream>>>(Wbd, 1024, xn, 1024, 1024, 128, bd_t, 16384);

  // fused ew + scan -> c_r, c_i
  scan_fused_kernel<<<256, blk, 0, stream>>>(bd_t, log_decay, frequency, b_sel, c_r, c_i);

  // transpose to [B*T,128] bf16
  transpose_cc_kernel<<<dim3(64, 4), blk, 0, stream>>>(c_r, c_i, cc);

  // fused gate + h-projection + residual -> xmid bf16   (grid 512, nx=4)
  gateh_kernel<<<512, blk512, 0, stream>>>(xn, Wgb, cc, Wef, x, b_g, xmid);

  // LN2 fused (bf16 in) -> xn bf16
  ln_fused_bf16_kernel<<<NROWS, blk, 0, stream>>>(xmid, g2, be2, xn);

  if (full) {
    // W1 full: mid = silu(xn @ W1^T + b1)  (grid 2048, nx=16)
    gemmB_kernel<1><<<2048, blk512, 0, stream>>>(
        xn, 1024, W1b, 1024, 1024, 16, b1, nullptr, nullptr, mid, 4096);
    // W2 full: out = xmid + b2 + mid @ W2^T  (grid 512, nx=4)
    gemmB_kernel<2><<<512, blk512, 0, stream>>>(
        mid, 4096, W2b, 4096, 4096, 4, b2, xmid, out, nullptr, 1024);
  } else {
    for (int h = 0; h < 2; ++h) {
      gemmB_kernel<1><<<1024, blk512, 0, stream>>>(
          xn, 1024, W1b + (size_t)h * 2048 * 1024, 1024, 1024, 8,
          b1 + h * 2048, nullptr, nullptr, mid, 2048);
      if (h == 0) {
        gemmB_kernel<2><<<512, blk512, 0, stream>>>(
            mid, 2048, W2b, 4096, 2048, 4, b2, xmid, out, nullptr, 1024);
      } else {
        gemmB_kernel<3><<<512, blk512, 0, stream>>>(
            mid, 2048, W2b + 2048, 4096, 2048, 4, nullptr, nullptr, out, nullptr, 1024);
      }
    }
  }
}

// Round 14
// 439.622 us; speedup vs baseline: 1.1335x; 1.1335x over previous
//
#include <hip/hip_runtime.h>
#include <math.h>

typedef __bf16 bf16_t;
typedef __attribute__((ext_vector_type(8))) __bf16 bf16x8;
typedef __attribute__((ext_vector_type(4))) __bf16 bf16x4;
typedef __attribute__((ext_vector_type(4))) float f32x4;

#define DMODEL 1024
#define NROWS  16384   // B*T
#define SEQLEN 4096

static __device__ __forceinline__ float sigmoidf_(float v) { return 1.f / (1.f + __expf(-v)); }
static __device__ __forceinline__ float tanhf_(float v) {
  v = fminf(fmaxf(v, -15.f), 15.f);
  float e = __expf(-2.f * v);
  return (1.f - e) / (1.f + e);
}

#define GLOAD16(gsrc, ldst) __builtin_amdgcn_global_load_lds(                     \
    (const __attribute__((address_space(1))) void*)(gsrc),                        \
    (__attribute__((address_space(3))) void*)(ldst), 16, 0, 0)

// ---------------- fused LayerNorm (f32 in): stats + apply + f32->bf16 ----------------
__global__ __launch_bounds__(256) void ln_fused_kernel(const float* __restrict__ x,
                                                       const float* __restrict__ g,
                                                       const float* __restrict__ b,
                                                       bf16_t* __restrict__ out) {
  int row = blockIdx.x;
  int tid = threadIdx.x;
  const float4* xr = (const float4*)(x + (size_t)row * DMODEL);
  float4 v = xr[tid];
  float s  = v.x + v.y + v.z + v.w;
  float s2 = v.x*v.x + v.y*v.y + v.z*v.z + v.w*v.w;
  #pragma unroll
  for (int off = 32; off > 0; off >>= 1) {
    s  += __shfl_down(s, off);
    s2 += __shfl_down(s2, off);
  }
  __shared__ float sh[4], sh2[4];
  int lane = tid & 63, wid = tid >> 6;
  if (lane == 0) { sh[wid] = s; sh2[wid] = s2; }
  __syncthreads();
  s  = sh[0] + sh[1] + sh[2] + sh[3];
  s2 = sh2[0] + sh2[1] + sh2[2] + sh2[3];
  float m = s * (1.f / DMODEL);
  float var = fmaxf(s2 * (1.f / DMODEL) - m * m, 0.f);
  float rs = rsqrtf(var + 1e-5f);
  float4 gv = *(const float4*)&g[tid * 4];
  float4 bv = *(const float4*)&b[tid * 4];
  union { bf16_t h[4]; float2 f2; } u;
  u.h[0] = (bf16_t)((v.x - m) * rs * gv.x + bv.x);
  u.h[1] = (bf16_t)((v.y - m) * rs * gv.y + bv.y);
  u.h[2] = (bf16_t)((v.z - m) * rs * gv.z + bv.z);
  u.h[3] = (bf16_t)((v.w - m) * rs * gv.w + bv.w);
  *(float2*)&out[(size_t)row * DMODEL + tid * 4] = u.f2;
}

// ---------------- fused LayerNorm (bf16 in) ----------------
__global__ __launch_bounds__(256) void ln_fused_bf16_kernel(const bf16_t* __restrict__ x,
                                                            const float* __restrict__ g,
                                                            const float* __restrict__ b,
                                                            bf16_t* __restrict__ out) {
  int row = blockIdx.x;
  int tid = threadIdx.x;
  bf16x4 hv = *(const bf16x4*)(x + (size_t)row * DMODEL + tid * 4);
  float v0 = (float)hv[0], v1 = (float)hv[1], v2 = (float)hv[2], v3 = (float)hv[3];
  float s  = v0 + v1 + v2 + v3;
  float s2 = v0*v0 + v1*v1 + v2*v2 + v3*v3;
  #pragma unroll
  for (int off = 32; off > 0; off >>= 1) {
    s  += __shfl_down(s, off);
    s2 += __shfl_down(s2, off);
  }
  __shared__ float sh[4], sh2[4];
  int lane = tid & 63, wid = tid >> 6;
  if (lane == 0) { sh[wid] = s; sh2[wid] = s2; }
  __syncthreads();
  s  = sh[0] + sh[1] + sh[2] + sh[3];
  s2 = sh2[0] + sh2[1] + sh2[2] + sh2[3];
  float m = s * (1.f / DMODEL);
  float var = fmaxf(s2 * (1.f / DMODEL) - m * m, 0.f);
  float rs = rsqrtf(var + 1e-5f);
  float4 gv = *(const float4*)&g[tid * 4];
  float4 bv = *(const float4*)&b[tid * 4];
  union { bf16_t h[4]; float2 f2; } u;
  u.h[0] = (bf16_t)((v0 - m) * rs * gv.x + bv.x);
  u.h[1] = (bf16_t)((v1 - m) * rs * gv.y + bv.y);
  u.h[2] = (bf16_t)((v2 - m) * rs * gv.z + bv.z);
  u.h[3] = (bf16_t)((v3 - m) * rs * gv.w + bv.w);
  *(float2*)&out[(size_t)row * DMODEL + tid * 4] = u.f2;
}

// ---------------- plain f32 -> bf16 convert ----------------
__global__ __launch_bounds__(256) void f32_to_bf16_kernel(const float* __restrict__ in,
                                                          bf16_t* __restrict__ out, int n) {
  int idx = (blockIdx.x * 256 + threadIdx.x) * 4;
  if (idx >= n) return;
  float4 v = *(const float4*)&in[idx];
  union { bf16_t h[4]; float2 f2; } u;
  u.h[0] = (bf16_t)v.x; u.h[1] = (bf16_t)v.y; u.h[2] = (bf16_t)v.z; u.h[3] = (bf16_t)v.w;
  *(float2*)&out[idx] = u.f2;
}

// ================= Engine B (r7-proven): 128x256 / BK=64 / single-buffer 48KB / 8 waves =======
// C[M,N] = A[M,K]*B[N,K]^T. 512 thr, waves 2(M)x4(N), wave tile 64x64 -> acc 64 f32.
// 2 barriers/K-tile; 2 blocks/CU co-resident hide the stage drain (m114). Swizzle: conflicts=0 (r7 PMC).
// EPI: 0 outf=acc; 1 outb=bf16(silu(acc+bias)); 2 outf=(float)resb+bias+acc; 3 outf+=acc;
//      4 outb=bf16(resf + sigmoid(acc+bias)*(float)auxb); 5 outb=bf16(acc)
template<int EPI>
__global__ __launch_bounds__(512, 4) void gemmB_kernel(
    const bf16_t* __restrict__ A, int lda,
    const bf16_t* __restrict__ B, int ldb, int K, int nx,
    const float* __restrict__ bias,
    const float* __restrict__ resf,
    const bf16_t* __restrict__ resb,
    const bf16_t* __restrict__ auxb,
    float* __restrict__ outf, bf16_t* __restrict__ outb, int ldout) {
  __shared__ __align__(128) bf16_t Asm[128 * 64];   // 16 KB
  __shared__ __align__(128) bf16_t Bsm[256 * 64];   // 32 KB
  const int nwg = gridDim.x;
  const int bid = blockIdx.x;
  const int lid = (bid & 7) * (nwg >> 3) + (bid >> 3);   // bijective XCD swizzle (nwg%8==0)
  const int n0 = (lid % nx) * 256;
  const int r0 = (lid / nx) * 128;

  const int tid = threadIdx.x;
  const int lane = tid & 63;
  const int w = tid >> 6;
  const int wr = w >> 2, wc = w & 3;        // 2 x 4 wave grid
  const int fr = lane & 15;
  const int q16 = (lane >> 4) * 16;         // k-byte base within 64-bf16 row half
  const int swz = (fr & 7) << 4;
  const int trow = tid >> 3;                // staging row 0..63
  const int scolb = ((tid & 7) ^ (trow & 7)) << 4;

  const size_t lda_b = (size_t)lda * 2;
  const size_t ldb_b = (size_t)ldb * 2;
  const char* Ab = (const char*)A;
  const char* Bb = (const char*)B;
  char* lA = (char*)Asm;
  char* lB = (char*)Bsm;

  f32x4 acc[4][4];
  #pragma unroll
  for (int m = 0; m < 4; ++m)
    #pragma unroll
    for (int n = 0; n < 4; ++n) acc[m][n] = (f32x4){0.f, 0.f, 0.f, 0.f};

  for (int kt = 0; kt < K; kt += 64) {
    const char* sa = Ab + (size_t)(r0 + trow) * lda_b + kt * 2 + scolb;
    GLOAD16(sa, lA + tid * 16);
    GLOAD16(sa + 64 * lda_b, lA + 8192 + tid * 16);
    const char* sb = Bb + (size_t)(n0 + trow) * ldb_b + kt * 2 + scolb;
    GLOAD16(sb, lB + tid * 16);
    GLOAD16(sb + 64 * ldb_b,  lB + 8192  + tid * 16);
    GLOAD16(sb + 128 * ldb_b, lB + 16384 + tid * 16);
    GLOAD16(sb + 192 * ldb_b, lB + 24576 + tid * 16);
    __syncthreads();
    #pragma unroll
    for (int kh = 0; kh < 2; ++kh) {
      bf16x8 af[4], bv[4];
      #pragma unroll
      for (int m = 0; m < 4; ++m)
        af[m] = *(const bf16x8*)(lA + (wr * 64 + m * 16 + fr) * 128 + ((kh * 64 + q16) ^ swz));
      #pragma unroll
      for (int n = 0; n < 4; ++n)
        bv[n] = *(const bf16x8*)(lB + (wc * 64 + n * 16 + fr) * 128 + ((kh * 64 + q16) ^ swz));
      #pragma unroll
      for (int m = 0; m < 4; ++m)
        #pragma unroll
        for (int n = 0; n < 4; ++n)
          acc[m][n] = __builtin_amdgcn_mfma_f32_16x16x32_bf16(af[m], bv[n], acc[m][n], 0, 0, 0);
    }
    __syncthreads();
  }

  const int rbase = (lane >> 4) * 4;
  #pragma unroll
  for (int mf = 0; mf < 4; ++mf) {
    #pragma unroll
    for (int n = 0; n < 4; ++n) {
      int row = r0 + wr * 64 + mf * 16 + rbase;
      int col = n0 + wc * 64 + n * 16 + fr;
      f32x4 v = acc[mf][n];
      #pragma unroll
      for (int j = 0; j < 4; ++j) {
        int r = row + j;
        float val = v[j];
        if (EPI == 0) {
          outf[(size_t)r * ldout + col] = val;
        } else if (EPI == 1) {
          float t2 = val + bias[col];
          t2 = t2 * sigmoidf_(t2);
          outb[(size_t)r * ldout + col] = (bf16_t)t2;
        } else if (EPI == 2) {
          outf[(size_t)r * ldout + col] =
              (float)resb[(size_t)r * 1024 + col] + bias[col] + val;
        } else if (EPI == 3) {
          outf[(size_t)r * ldout + col] += val;
        } else if (EPI == 4) {
          size_t idx = (size_t)r * 1024 + col;
          outb[idx] = (bf16_t)(resf[idx] + sigmoidf_(val + bias[col]) * (float)auxb[idx]);
        } else {
          outb[(size_t)r * ldout + col] = (bf16_t)val;
        }
      }
    }
  }
}

// ---------------- legacy 128x128 engine (beta/delta swapped GEMM only) ----------------
template<int EPI>
__global__ __launch_bounds__(256) void gemm_bf16_kernel(
    const bf16_t* __restrict__ A, int lda,
    const bf16_t* __restrict__ B, int ldb, int K, int nx,
    float* __restrict__ outf, int ldout) {
  __shared__ __align__(16) bf16_t As[128 * 32];
  __shared__ __align__(16) bf16_t Bs[128 * 32];
  const int nwg = gridDim.x;
  const int bid = blockIdx.x;
  const int lid = (bid & 7) * (nwg >> 3) + (bid >> 3);
  const int n0 = (lid % nx) * 128;
  const int r0 = (lid / nx) * 128;

  const int tid = threadIdx.x;
  const int lane = tid & 63;
  const int w = tid >> 6;
  const int wr = w >> 1, wc = w & 1;
  const int srow0 = tid >> 2;
  const int srow1 = 64 + (tid >> 2);
  const int skk = (tid & 3) * 8;
  const int fr = lane & 15;
  const int ko = (lane >> 4) * 8;

  f32x4 acc[4][4];
  #pragma unroll
  for (int m = 0; m < 4; ++m)
    #pragma unroll
    for (int n = 0; n < 4; ++n) acc[m][n] = (f32x4){0.f, 0.f, 0.f, 0.f};

  for (int k0 = 0; k0 < K; k0 += 32) {
    GLOAD16(A + (size_t)(r0 + srow0) * lda + k0 + skk, (char*)As + w * 1024);
    GLOAD16(A + (size_t)(r0 + srow1) * lda + k0 + skk, (char*)As + 4096 + w * 1024);
    GLOAD16(B + (size_t)(n0 + srow0) * ldb + k0 + skk, (char*)Bs + w * 1024);
    GLOAD16(B + (size_t)(n0 + srow1) * ldb + k0 + skk, (char*)Bs + 4096 + w * 1024);
    __syncthreads();
    bf16x8 af[4], bfr[4];
    #pragma unroll
    for (int m = 0; m < 4; ++m)
      af[m] = *(const bf16x8*)&As[(wr * 64 + m * 16 + fr) * 32 + ko];
    #pragma unroll
    for (int n = 0; n < 4; ++n)
      bfr[n] = *(const bf16x8*)&Bs[(wc * 64 + n * 16 + fr) * 32 + ko];
    #pragma unroll
    for (int m = 0; m < 4; ++m)
      #pragma unroll
      for (int n = 0; n < 4; ++n)
        acc[m][n] = __builtin_amdgcn_mfma_f32_16x16x32_bf16(af[m], bfr[n], acc[m][n], 0, 0, 0);
    __syncthreads();
  }

  const int rbase = (lane >> 4) * 4;
  #pragma unroll
  for (int m = 0; m < 4; ++m) {
    #pragma unroll
    for (int n = 0; n < 4; ++n) {
      int row = r0 + wr * 64 + m * 16 + rbase;
      int col = n0 + wc * 64 + n * 16 + fr;
      f32x4 v = acc[m][n];
      #pragma unroll
      for (int j = 0; j < 4; ++j)
        outf[(size_t)(row + j) * ldout + col] = v[j];
    }
  }
}

// ---------------- fused ew + scan: bd_t[256][16384] -> c_r,c_i in [B,K,T] ----------------
// One block per (b,k). Reads 4 contiguous rows of bd_t (coalesced), computes a,b in
// registers (fully unrolled -> static indexing), Hillis-Steele block scan, writes c.
__global__ __launch_bounds__(256) void scan_fused_kernel(
    const float* __restrict__ bdt,
    const float* __restrict__ log_decay, const float* __restrict__ frequency,
    const float* __restrict__ b_sel,
    float* __restrict__ c_r, float* __restrict__ c_i) {
  int seq = blockIdx.x;
  int bb = seq >> 6, k = seq & 63;
  int tid = threadIdx.x;
  size_t col = (size_t)bb * 4096 + tid * 16;
  const f32x4* pbr = (const f32x4*)(bdt + (size_t)k * 16384 + col);
  const f32x4* pbi = (const f32x4*)(bdt + (size_t)(64 + k) * 16384 + col);
  const f32x4* pdd = (const f32x4*)(bdt + (size_t)(128 + k) * 16384 + col);
  const f32x4* pdf = (const f32x4*)(bdt + (size_t)(192 + k) * 16384 + col);
  const float ld = log_decay[k], fq = frequency[k];
  const float bsd = b_sel[k], bsf = b_sel[64 + k];

  float arv[16], aiv[16], brv[16], biv[16];
  float Ar = 1.f, Ai = 0.f, Br = 0.f, Bi = 0.f;
  #pragma unroll
  for (int g = 0; g < 4; ++g) {
    f32x4 vbr = pbr[g], vbi = pbi[g], vdd = pdd[g], vdf = pdf[g];
    #pragma unroll
    for (int j = 0; j < 4; ++j) {
      int s = g * 4 + j;
      float mag = sigmoidf_(ld + 0.1f * tanhf_(vdd[j] + bsd));
      float f = fq + 0.05f * tanhf_(vdf[j] + bsf);
      float sn, cs;
      __sincosf(f, &sn, &cs);
      float ar = mag * cs, ai = mag * sn;
      float br = vbr[j], bi = vbi[j];
      arv[s] = ar; aiv[s] = ai; brv[s] = br; biv[s] = bi;
      float nBr = ar * Br - ai * Bi + br;
      float nBi = ar * Bi + ai * Br + bi;
      Br = nBr; Bi = nBi;
      float nAr = ar * Ar - ai * Ai;
      float nAi = ar * Ai + ai * Ar;
      Ar = nAr; Ai = nAi;
    }
  }

  __shared__ float sAr[256], sAi[256], sBr[256], sBi[256];
  sAr[tid] = Ar; sAi[tid] = Ai; sBr[tid] = Br; sBi[tid] = Bi;
  for (int off = 1; off < 256; off <<= 1) {
    __syncthreads();
    float pAr = 0.f, pAi = 0.f, pBr = 0.f, pBi = 0.f;
    if (tid >= off) { pAr = sAr[tid - off]; pAi = sAi[tid - off]; pBr = sBr[tid - off]; pBi = sBi[tid - off]; }
    __syncthreads();
    if (tid >= off) {
      float cAr = sAr[tid], cAi = sAi[tid], cBr = sBr[tid], cBi = sBi[tid];
      float nBr = cAr * pBr - cAi * pBi + cBr;
      float nBi = cAr * pBi + cAi * pBr + cBi;
      float nAr = cAr * pAr - cAi * pAi;
      float nAi = cAr * pAi + cAi * pAr;
      sAr[tid] = nAr; sAi[tid] = nAi; sBr[tid] = nBr; sBi[tid] = nBi;
    }
  }
  __syncthreads();
  float cr = (tid > 0) ? sBr[tid - 1] : 0.f;
  float ci = (tid > 0) ? sBi[tid - 1] : 0.f;

  float* outr = c_r + (size_t)seq * 4096 + tid * 16;
  float* outi = c_i + (size_t)seq * 4096 + tid * 16;
  #pragma unroll
  for (int g = 0; g < 4; ++g) {
    f32x4 vr, vi;
    #pragma unroll
    for (int j = 0; j < 4; ++j) {
      int s = g * 4 + j;
      float nr = arv[s] * cr - aiv[s] * ci + brv[s];
      float ni = arv[s] * ci + aiv[s] * cr + biv[s];
      cr = nr; ci = ni;
      vr[j] = cr; vi[j] = ci;
    }
    *(f32x4*)(outr + g * 4) = vr;
    *(f32x4*)(outi + g * 4) = vi;
  }
}

// ---------------- transpose c[B,K,T] -> cc[B*T, 128] bf16 ----------------
__global__ __launch_bounds__(256) void transpose_cc_kernel(
    const float* __restrict__ c_r, const float* __restrict__ c_i,
    bf16_t* __restrict__ cc) {
  __shared__ float Tr[64][65];
  __shared__ float Ti[64][65];
  int t0 = blockIdx.x * 64;
  int bb = blockIdx.y;
  int tid = threadIdx.x;
  int tt = tid & 63;
  int q = tid >> 6;
  #pragma unroll
  for (int p = 0; p < 16; ++p) {
    int k = p * 4 + q;
    size_t src = ((size_t)bb * 64 + k) * 4096 + t0 + tt;
    Tr[tt][k] = c_r[src];
    Ti[tt][k] = c_i[src];
  }
  __syncthreads();
  #pragma unroll
  for (int p = 0; p < 16; ++p) {
    int tt2 = p * 4 + q;
    int k = tid & 63;
    size_t row = (size_t)bb * 4096 + t0 + tt2;
    cc[row * 128 + k] = (bf16_t)Tr[tt2][k];
    cc[row * 128 + 64 + k] = (bf16_t)Ti[tt2][k];
  }
}

// ---------------- fold R into W_out: Weff[d][col] (bf16 out) ----------------
__global__ __launch_bounds__(256) void weff_kernel(const float* __restrict__ W_out,
                                                   const float* __restrict__ R,
                                                   bf16_t* __restrict__ Weff) {
  int idx = blockIdx.x * 256 + threadIdx.x;   // < 1024*128
  int d = idx >> 7, col = idx & 127;
  int k = col & 63, h = k >> 4, kk = k & 15;
  int off = (col < 64) ? 0 : 64;
  float s = 0.f;
  #pragma unroll
  for (int j = 0; j < 16; ++j)
    s += W_out[d * 128 + off + h * 16 + j] * R[h * 256 + j * 16 + kk];
  Weff[idx] = (bf16_t)s;
}

extern "C" void kernel_launch(void* const* d_in, const int* in_sizes, int n_in,
                              void* d_out, int out_size, void* d_ws, size_t ws_size,
                              hipStream_t stream) {
  (void)in_sizes; (void)n_in; (void)out_size;
  const float* x         = (const float*)d_in[0];
  const float* W_in      = (const float*)d_in[1];
  const float* log_decay = (const float*)d_in[2];
  const float* frequency = (const float*)d_in[3];
  const float* W_sel     = (const float*)d_in[4];
  const float* b_sel     = (const float*)d_in[5];
  const float* R         = (const float*)d_in[6];
  const float* W_out     = (const float*)d_in[7];
  const float* W_g       = (const float*)d_in[8];
  const float* b_g       = (const float*)d_in[9];
  const float* g1        = (const float*)d_in[10];
  const float* be1       = (const float*)d_in[11];
  const float* g2        = (const float*)d_in[12];
  const float* be2       = (const float*)d_in[13];
  const float* W1        = (const float*)d_in[14];
  const float* b1        = (const float*)d_in[15];
  const float* W2        = (const float*)d_in[16];
  const float* b2        = (const float*)d_in[17];
  float* out = (float*)d_out;
  float* ws  = (float*)d_ws;

  const size_t M1 = (size_t)1 << 20;
  // full path usage: mid 32M @0 (R1 inside) + xmid 8M + hbufb 8M + xn 8M + weights ~4.7M = 60.7M f32
  const bool full = ws_size >= (size_t)61 * M1 * sizeof(float);   // 244 MB

  // R1 (dead before W1; overlapped by mid):
  float* bd_t = ws;                        // [0,4M)   256 x 16384 f32
  float* c_r  = ws + 4 * M1;               // [4,8M)
  float* c_i  = ws + 8 * M1;               // [8,12M)
  bf16_t* cc  = (bf16_t*)(ws + 12 * M1);   // [12,13M) 16384 x 128 bf16
  bf16_t* mid = (bf16_t*)ws;               // full: 16384x4096 bf16 [0,32M); chunked: 16384x2048 [0,16M)
  size_t o = full ? 32 * M1 : 16 * M1;
  bf16_t* xmid  = (bf16_t*)(ws + o);            // 16384x1024 bf16 (residual stream)
  bf16_t* hbufb = (bf16_t*)(ws + o + 8 * M1);   // 16384x1024 bf16
  bf16_t* xn    = (bf16_t*)(ws + o + 16 * M1);  // 16384x1024 bf16
  size_t wb = o + 24 * M1;
  bf16_t* Wbd = (bf16_t*)(ws + wb);                        // 256 x 1024
  bf16_t* Wgb = (bf16_t*)(ws + wb + (128 << 10));          // 1024 x 1024
  bf16_t* W1b = (bf16_t*)(ws + wb + (640 << 10));          // 4096 x 1024
  bf16_t* W2b = (bf16_t*)(ws + wb + 2 * M1 + (640 << 10)); // 1024 x 4096
  bf16_t* Wef = (bf16_t*)(ws + wb + 4 * M1 + (640 << 10)); // 1024 x 128

  dim3 blk(256);
  dim3 blk512(512);

  // LN1 fused -> xn bf16
  ln_fused_kernel<<<NROWS, blk, 0, stream>>>(x, g1, be1, xn);

  // weight conversions
  f32_to_bf16_kernel<<<128, blk, 0, stream>>>(W_in, Wbd, 128 * 1024);
  f32_to_bf16_kernel<<<128, blk, 0, stream>>>(W_sel, Wbd + 128 * 1024, 128 * 1024);
  f32_to_bf16_kernel<<<1024, blk, 0, stream>>>(W_g, Wgb, 1024 * 1024);
  f32_to_bf16_kernel<<<4096, blk, 0, stream>>>(W1, W1b, 4 * 1024 * 1024);
  f32_to_bf16_kernel<<<4096, blk, 0, stream>>>(W2, W2b, 4 * 1024 * 1024);
  weff_kernel<<<512, blk, 0, stream>>>(W_out, R, Wef);

  // beta/delta GEMM SWAPPED: bd_t[j][t] = Wbd[j]·xn[t]  (M=256,N=16384,K=1024; grid 256, nx=128)
  gemm_bf16_kernel<0><<<256, blk, 0, stream>>>(Wbd, 1024, xn, 1024, 1024, 128, bd_t, 16384);

  // fused ew + scan -> c_r, c_i
  scan_fused_kernel<<<256, blk, 0, stream>>>(bd_t, log_decay, frequency, b_sel, c_r, c_i);

  // transpose to [B*T,128] bf16
  transpose_cc_kernel<<<dim3(64, 4), blk, 0, stream>>>(c_r, c_i, cc);

  // h-projection: hbufb = bf16(cc @ Weff^T)   (grid 512, nx=4)
  gemmB_kernel<5><<<512, blk512, 0, stream>>>(
      cc, 128, Wef, 128, 128, 4, nullptr, nullptr, nullptr, nullptr, nullptr, hbufb, 1024);

  // gate GEMM + fuse: xmid(bf16) = x + sigmoid(xn@Wg^T + b_g) * hbufb   (grid 512, nx=4)
  gemmB_kernel<4><<<512, blk512, 0, stream>>>(
      xn, 1024, Wgb, 1024, 1024, 4, b_g, x, nullptr, hbufb, nullptr, xmid, 1024);

  // LN2 fused (bf16 in) -> xn bf16
  ln_fused_bf16_kernel<<<NROWS, blk, 0, stream>>>(xmid, g2, be2, xn);

  if (full) {
    // W1 full: mid = silu(xn @ W1^T + b1)  (grid 2048, nx=16)
    gemmB_kernel<1><<<2048, blk512, 0, stream>>>(
        xn, 1024, W1b, 1024, 1024, 16, b1, nullptr, nullptr, nullptr, nullptr, mid, 4096);
    // W2 full: out = xmid + b2 + mid @ W2^T  (grid 512, nx=4)
    gemmB_kernel<2><<<512, blk512, 0, stream>>>(
        mid, 4096, W2b, 4096, 4096, 4, b2, nullptr, xmid, nullptr, out, nullptr, 1024);
  } else {
    for (int h = 0; h < 2; ++h) {
      gemmB_kernel<1><<<1024, blk512, 0, stream>>>(
          xn, 1024, W1b + (size_t)h * 2048 * 1024, 1024, 1024, 8,
          b1 + h * 2048, nullptr, nullptr, nullptr, nullptr, mid, 2048);
      if (h == 0) {
        gemmB_kernel<2><<<512, blk512, 0, stream>>>(
            mid, 2048, W2b, 4096, 2048, 4, b2, nullptr, xmid, nullptr, out, nullptr, 1024);
      } else {
        gemmB_kernel<3><<<512, blk512, 0, stream>>>(
            mid, 2048, W2b + 2048, 4096, 2048, 4, nullptr, nullptr, nullptr, nullptr, out, nullptr, 1024);
      }
    }
  }
}